// Round 12
// baseline (737.798 us; speedup 1.0000x reference)
//
#include <hip/hip_runtime.h>

#define N_VOX 100000
#define K_OFF 27
#define M_PAIR 60000
#define NPAIR (K_OFF * M_PAIR)
#define CIN 64
#define COUT 64
#define BN_EPS 1e-5f

// bucketed counting "sort": pair records scattered into per-bucket arrays
// (1.62M direct global returning atomics = 72us at ~22G/s; bucketing needs
// only ~155K global atomics).
#define VB_SHIFT 8
#define VB (1 << VB_SHIFT)                       // 256 voxels per bucket
#define NB ((N_VOX + VB - 1) / VB)               // 391 buckets
#define BCAP 5120                                // mean 4147 + 15 sigma
#define PPT 16                                   // pairs per thread, scatter
#define PA_PAIRS (256 * PPT)                     // 4096 per block
#define PA_GRID ((NPAIR + PA_PAIRS - 1) / PA_PAIRS)  // 396

// fused gather-conv: one block per QUARTER bucket (64 voxels). The GEMM runs
// INSIDE the gather block, accumulating into an LDS f32 accumulator — the
// 414MB contrib round-trip (207 write + 207 read) is eliminated entirely.
#define QSPLIT 4
#define QVOX (VB / QSPLIT)                       // 64 voxels per block
#define QCAP 1280                                // mean 1037 + ~7.5 sigma
#define ACC_STRIDE 66                            // pad: banks = (66v+ch)%32 spreads quads

typedef __attribute__((ext_vector_type(8))) short bf16x8;
typedef __attribute__((ext_vector_type(4))) float f32x4;

__device__ __forceinline__ unsigned short f32_to_bf16(float f) {
    unsigned int u = __float_as_uint(f);
    u += 0x7FFFu + ((u >> 16) & 1u);
    return (unsigned short)(u >> 16);
}
__device__ __forceinline__ float bf16_to_f32(unsigned short b) {
    return __uint_as_float(((unsigned int)b) << 16);
}

// ---------- prep + bucket scatter: fb bf16, W^T bf16, pair records ----------
__global__ __launch_bounds__(256) void prep_scatter_kernel(
    const int* __restrict__ oix,
    unsigned int* __restrict__ recs, int* __restrict__ bucketCount,
    const float* __restrict__ feats, unsigned short* __restrict__ fb,
    const float* __restrict__ W, unsigned short* __restrict__ Wt)
{
    __shared__ int lhist[NB];
    __shared__ int gbase[NB];
    const int t = threadIdx.x;
    for (int i = t; i < NB; i += 256) lhist[i] = 0;
    __syncthreads();

    const int base = blockIdx.x * PA_PAIRS;
    int vsave[PPT];
    int lpos[PPT];
#pragma unroll
    for (int i = 0; i < PPT; ++i) {
        const int e = base + i * 256 + t;
        int v = -1, lp = 0;
        if (e < NPAIR) {
            v = oix[e];
            lp = atomicAdd(&lhist[v >> VB_SHIFT], 1);   // LDS returning atomic
        }
        vsave[i] = v;
        lpos[i] = lp;
    }
    __syncthreads();
    for (int i = t; i < NB; i += 256) {
        const int c = lhist[i];
        gbase[i] = c ? atomicAdd(&bucketCount[i], c) : 0;  // 1 global atomic/(block,bucket)
    }
    __syncthreads();
#pragma unroll
    for (int i = 0; i < PPT; ++i) {
        const int v = vsave[i];
        if (v >= 0) {
            const int e = base + i * 256 + t;
            const int b = v >> VB_SHIFT;
            const int idx = gbase[b] + lpos[i];
            if (idx < BCAP)
                recs[(size_t)b * BCAP + idx] =
                    ((unsigned int)e << VB_SHIFT) | (unsigned int)(v & (VB - 1));
        }
    }

    // fused streaming prep (grid-stride)
    const int gid = blockIdx.x * 256 + t;
    const int nt = PA_GRID * 256;
    for (int e4i = gid; e4i < (N_VOX * CIN) / 4; e4i += nt) {
        const int e4 = e4i * 4;
        const float4 v = *(const float4*)(feats + e4);
        ushort4 b;
        b.x = f32_to_bf16(v.x);
        b.y = f32_to_bf16(v.y);
        b.z = f32_to_bf16(v.z);
        b.w = f32_to_bf16(v.w);
        *(ushort4*)(fb + e4) = b;
    }
    for (int e = gid; e < K_OFF * CIN * COUT; e += nt) {
        const int k = e / (CIN * COUT);
        const int r = e % (CIN * COUT);
        Wt[k * CIN * COUT + (r % COUT) * CIN + (r / COUT)] = f32_to_bf16(W[e]);
    }
}

// ---------- fused gather-conv-BN: per-quarter-bucket GEMM into LDS f32 acc ----------
// Pair list binned by k in LDS; wave wid owns k in {wid, wid+4, ...}: loads
// W_k fragments once (8KB, L2-hot), MFMAs 16-pair tiles (fb rows gathered
// from the MALL-resident 12.8MB fb), scatter-adds rows into accS via LDS
// float atomics. Epilogue: BN fold + ReLU, coalesced f32 stores.
__global__ __launch_bounds__(256) void gconv_kernel(
    const unsigned int* __restrict__ recs, const int* __restrict__ bucketCount,
    const unsigned short* __restrict__ fb, const unsigned short* __restrict__ Wt,
    const int* __restrict__ in_idx,
    const float* __restrict__ gamma, const float* __restrict__ beta,
    const float* __restrict__ rmean, const float* __restrict__ rvar,
    float* __restrict__ out)
{
    __shared__ int khist[32];
    __shared__ int kbase[32];
    __shared__ int kcur[32];
    __shared__ unsigned int lpermK[QCAP];
    __shared__ float accS[QVOX * ACC_STRIDE];     // 16.9 KB
    __shared__ float s_sc[COUT], s_sh[COUT];

    const int blk = blockIdx.x;          // 0 .. NB*QSPLIT-1
    const int b = blk >> 2;
    const int q = blk & 3;
    const int t = threadIdx.x;
    if (t < 32) { khist[t] = 0; kcur[t] = 0; }
    if (t < COUT) {
        const float inv = rsqrtf(rvar[t] + BN_EPS);
        const float sc = inv * gamma[t];
        s_sc[t] = sc;
        s_sh[t] = beta[t] - rmean[t] * sc;
    }
    for (int i = t; i < QVOX * ACC_STRIDE; i += 256) accS[i] = 0.f;
    __syncthreads();

    int bc = bucketCount[b];
    if (bc > BCAP) bc = BCAP;
    const unsigned int* r = recs + (size_t)b * BCAP;
    // pass 1: count by k (filtered to this quarter)
    for (int i = t; i < bc; i += 256) {
        const unsigned int rec = r[i];
        const int vl = rec & (VB - 1);
        if ((vl >> 6) == q) atomicAdd(&khist[(rec >> VB_SHIFT) / M_PAIR], 1);
    }
    __syncthreads();
    if (t == 0) {
        int s = 0;
        for (int k = 0; k < K_OFF; ++k) { kbase[k] = s; s += khist[k]; }
    }
    __syncthreads();
    // pass 2: scatter (vl6<<21 | e) into k-sorted LDS list (recs re-read L2-hot)
    for (int i = t; i < bc; i += 256) {
        const unsigned int rec = r[i];
        const int vl = rec & (VB - 1);
        if ((vl >> 6) == q) {
            const unsigned int e = rec >> VB_SHIFT;     // < 2^21
            const int k = (int)(e / M_PAIR);
            const int p = kbase[k] + atomicAdd(&kcur[k], 1);
            if (p < QCAP)
                lpermK[p] = ((unsigned int)(vl & 63) << 21) | e;
        }
    }
    __syncthreads();

    // MFMA phase: wave wid handles k = wid, wid+4, ... (no barriers needed;
    // all accumulator writes are LDS atomics)
    const int lane = t & 63;
    const int wid = t >> 6;
    const int col = lane & 15;
    const int quad = lane >> 4;
    for (int k = wid; k < K_OFF; k += 4) {
        int cnt = khist[k];
        const int base = kbase[k];
        if (base >= QCAP) continue;
        if (base + cnt > QCAP) cnt = QCAP - base;
        if (cnt <= 0) continue;

        bf16x8 Bf[4][2];
        const short* Wk = (const short*)(Wt + k * CIN * COUT);
#pragma unroll
        for (int tt = 0; tt < 4; ++tt) {
            const short* p = Wk + (tt * 16 + col) * CIN + quad * 8;
            Bf[tt][0] = *(const bf16x8*)(p);
            Bf[tt][1] = *(const bf16x8*)(p + 32);
        }

        const int ntile = (cnt + 15) >> 4;
        for (int tile = 0; tile < ntile; ++tile) {
            const int pr = tile * 16 + col;          // this lane's A-row (pair)
            bf16x8 A0 = {0, 0, 0, 0, 0, 0, 0, 0};
            bf16x8 A1 = {0, 0, 0, 0, 0, 0, 0, 0};
            if (pr < cnt) {
                const unsigned int e = lpermK[base + pr] & 0x1FFFFFu;
                const int rin = in_idx[e];
                const short* fp = (const short*)fb + (size_t)rin * CIN + quad * 8;
                A0 = *(const bf16x8*)(fp);
                A1 = *(const bf16x8*)(fp + 32);
            }
            f32x4 acc[4];
#pragma unroll
            for (int tt = 0; tt < 4; ++tt) {
                f32x4 z = {0.f, 0.f, 0.f, 0.f};
                acc[tt] = __builtin_amdgcn_mfma_f32_16x16x32_bf16(A0, Bf[tt][0], z, 0, 0, 0);
                acc[tt] = __builtin_amdgcn_mfma_f32_16x16x32_bf16(A1, Bf[tt][1], acc[tt], 0, 0, 0);
            }
            // scatter-add rows into the per-voxel accumulator
#pragma unroll
            for (int rr = 0; rr < 4; ++rr) {
                const int row = tile * 16 + quad * 4 + rr;
                if (row < cnt) {
                    const int vl = (int)(lpermK[base + row] >> 21);
                    float* ap = accS + vl * ACC_STRIDE + col;
#pragma unroll
                    for (int tt = 0; tt < 4; ++tt)
                        atomicAdd(ap + tt * 16, acc[tt][rr]);
                }
            }
        }
    }
    __syncthreads();

    // epilogue: BN + ReLU, coalesced writes
    const int vbase = b * VB + q * QVOX;
    for (int u = t; u < QVOX * 16; u += 256) {    // 1024 float4 units
        const int vl = u >> 4;
        const int ch = (u & 15) * 4;
        const int v = vbase + vl;
        if (v < N_VOX) {
            const float* ap = accS + vl * ACC_STRIDE + ch;
            float4 rr;
            rr.x = fmaxf(fmaf(ap[0], s_sc[ch + 0], s_sh[ch + 0]), 0.f);
            rr.y = fmaxf(fmaf(ap[1], s_sc[ch + 1], s_sh[ch + 1]), 0.f);
            rr.z = fmaxf(fmaf(ap[2], s_sc[ch + 2], s_sh[ch + 2]), 0.f);
            rr.w = fmaxf(fmaf(ap[3], s_sc[ch + 3], s_sh[ch + 3]), 0.f);
            *(float4*)(out + (size_t)v * 64 + ch) = rr;
        }
    }
}

// ---------- fallback (atomic path, used if ws too small) ----------
__global__ __launch_bounds__(256) void prep_small_kernel(
    const float* __restrict__ feats, unsigned short* __restrict__ fb,
    float* __restrict__ out, const float* __restrict__ W,
    unsigned short* __restrict__ Wt)
{
    const int e = blockIdx.x * blockDim.x + threadIdx.x;
    if (e < (N_VOX * CIN) / 4) {
        const int e4 = e * 4;
        const float4 v = *(const float4*)(feats + e4);
        ushort4 b;
        b.x = f32_to_bf16(v.x);
        b.y = f32_to_bf16(v.y);
        b.z = f32_to_bf16(v.z);
        b.w = f32_to_bf16(v.w);
        *(ushort4*)(fb + e4) = b;
        *(float4*)(out + e4) = make_float4(0.f, 0.f, 0.f, 0.f);
    }
    if (e < K_OFF * CIN * COUT) {
        const int k = e / (CIN * COUT);
        const int r = e % (CIN * COUT);
        Wt[k * CIN * COUT + (r % COUT) * CIN + (r / COUT)] = f32_to_bf16(W[e]);
    }
}

__global__ __launch_bounds__(256) void conv_atomic_kernel(
    const unsigned short* __restrict__ fb, const unsigned short* __restrict__ Wt,
    const int* __restrict__ in_idx, const int* __restrict__ out_idx,
    float* __restrict__ out)
{
    const int k = blockIdx.y;
    const int lane = threadIdx.x & 63;
    const int wave = blockIdx.x * 4 + (threadIdx.x >> 6);
    const int col = lane & 15;
    const int quad = lane >> 4;
    bf16x8 Bf[4][2];
    const short* Wk = (const short*)(Wt + k * CIN * COUT);
#pragma unroll
    for (int t = 0; t < 4; ++t) {
        const short* p = Wk + (t * 16 + col) * CIN + quad * 8;
        Bf[t][0] = *(const bf16x8*)(p);
        Bf[t][1] = *(const bf16x8*)(p + 32);
    }
    const int base = k * M_PAIR;
    for (int tile = wave; tile < M_PAIR / 16; tile += 128) {
        const int m0 = base + tile * 16;
        const int rin = in_idx[m0 + col];
        const short* fp = (const short*)fb + (size_t)rin * CIN + quad * 8;
        const bf16x8 A0 = *(const bf16x8*)(fp);
        const bf16x8 A1 = *(const bf16x8*)(fp + 32);
        f32x4 acc[4];
#pragma unroll
        for (int t = 0; t < 4; ++t) {
            f32x4 z = {0.f, 0.f, 0.f, 0.f};
            acc[t] = __builtin_amdgcn_mfma_f32_16x16x32_bf16(A0, Bf[t][0], z, 0, 0, 0);
            acc[t] = __builtin_amdgcn_mfma_f32_16x16x32_bf16(A1, Bf[t][1], acc[t], 0, 0, 0);
        }
        int vo[4];
#pragma unroll
        for (int r = 0; r < 4; ++r) vo[r] = out_idx[m0 + quad * 4 + r];
#pragma unroll
        for (int r = 0; r < 4; ++r) {
            float* op = out + (size_t)vo[r] * COUT + col;
#pragma unroll
            for (int t = 0; t < 4; ++t) atomicAdd(op + t * 16, acc[t][r]);
        }
    }
}

__global__ __launch_bounds__(256) void bn_relu_kernel(
    float* __restrict__ out,
    const float* __restrict__ gamma, const float* __restrict__ beta,
    const float* __restrict__ mean, const float* __restrict__ var)
{
    const int e = blockIdx.x * blockDim.x + threadIdx.x;
    if (e >= N_VOX * COUT) return;
    const int c = e & (COUT - 1);
    const float inv = rsqrtf(var[c] + BN_EPS);
    const float y = (out[e] - mean[c]) * (inv * gamma[c]) + beta[c];
    out[e] = fmaxf(y, 0.f);
}

// ---------- host ----------
extern "C" void kernel_launch(void* const* d_in, const int* in_sizes, int n_in,
                              void* d_out, int out_size, void* d_ws, size_t ws_size,
                              hipStream_t stream) {
    const float* feats = (const float*)d_in[0];
    const float* W     = (const float*)d_in[1];
    const float* gamma = (const float*)d_in[2];
    const float* beta  = (const float*)d_in[3];
    const float* rmean = (const float*)d_in[4];
    const float* rvar  = (const float*)d_in[5];
    const int* in_idx  = (const int*)d_in[6];
    const int* out_idx = (const int*)d_in[7];
    float* out = (float*)d_out;

    char* ws = (char*)d_ws;
    size_t off = 0;
    auto alloc = [&](size_t bytes) {
        size_t p = off;
        off = (off + bytes + 255) & ~(size_t)255;
        return p;
    };
    const size_t o_fb   = alloc((size_t)N_VOX * CIN * 2);
    const size_t o_wt   = alloc((size_t)K_OFF * CIN * COUT * 2);
    const size_t o_bc   = alloc((size_t)NB * 4);              // bucketCount
    const size_t o_recs = alloc((size_t)NB * BCAP * 4);
    const bool big = (ws_size >= off);       // constant across calls -> graph-safe

    unsigned short* fb  = (unsigned short*)(ws + o_fb);
    unsigned short* Wt  = (unsigned short*)(ws + o_wt);
    int* bucketCount    = (int*)(ws + o_bc);
    unsigned int* recs  = (unsigned int*)(ws + o_recs);

    if (big) {
        hipError_t _e = hipMemsetAsync(bucketCount, 0, (size_t)NB * 4, stream);
        (void)_e;
        prep_scatter_kernel<<<PA_GRID, 256, 0, stream>>>(
            out_idx, recs, bucketCount, feats, fb, W, Wt);
        gconv_kernel<<<NB * QSPLIT, 256, 0, stream>>>(
            recs, bucketCount, fb, Wt, in_idx,
            gamma, beta, rmean, rvar, out);
    } else {
        const int ptot = (N_VOX * CIN) / 4;
        prep_small_kernel<<<(ptot + 255) / 256, 256, 0, stream>>>(feats, fb, out, W, Wt);
        conv_atomic_kernel<<<dim3(32, K_OFF), 256, 0, stream>>>(fb, Wt, in_idx, out_idx, out);
        const int total_e = N_VOX * COUT;
        bn_relu_kernel<<<(total_e + 255) / 256, 256, 0, stream>>>(out, gamma, beta, rmean, rvar);
    }
}

// Round 13
// 226.160 us; speedup vs baseline: 3.2623x; 3.2623x over previous
//
#include <hip/hip_runtime.h>

#define N_VOX 100000
#define K_OFF 27
#define M_PAIR 60000
#define NPAIR (K_OFF * M_PAIR)
#define CIN 64
#define COUT 64
#define BN_EPS 1e-5f

// pair->slot assignment via bucketed counting sort (direct global atomics run
// at ~22G/s = 72us for 1.62M; bucketing cuts global atomics to ~155K and the
// scatter runs INSIDE conv, overlapped with its BW-bound stream):
#define VB_SHIFT 8
#define VB (1 << VB_SHIFT)                       // 256 voxels per bucket
#define NB ((N_VOX + VB - 1) / VB)               // 391 buckets
#define BCAP 5120                                // mean 4147 + 15 sigma
#define PPT 16                                   // pairs per thread, bucket phase
#define PA_PAIRS (256 * PPT)                     // 4096 per bucketing block
#define PA_GRID ((NPAIR + PA_PAIRS - 1) / PA_PAIRS)  // 396

// fused gather: one block per QUARTER bucket (64 voxels). Whole-bucket blocks
// (391 = 1.53/CU) would hit the 2-vs-1 block quantization wall; quarters give
// 1564 blocks = 6.1/CU (~15% tail). Pair-list lives in LDS, never in global.
#define QSPLIT 4
#define QVOX (VB / QSPLIT)                       // 64 voxels per block
#define QCAP 1280                                // mean 1037 + ~7.5 sigma

#define TILES_PER_WAVE 10
#define WAVES_PER_K (M_PAIR / 16 / TILES_PER_WAVE)   // 375
#define CONV_BLOCKS_X ((WAVES_PER_K + 3) / 4)        // 94

typedef __attribute__((ext_vector_type(8))) short bf16x8;
typedef __attribute__((ext_vector_type(8))) unsigned short u16x8;
typedef __attribute__((ext_vector_type(4))) unsigned int u32x4;
typedef __attribute__((ext_vector_type(4))) float f32x4;

__device__ __forceinline__ unsigned short f32_to_bf16(float f) {
    unsigned int u = __float_as_uint(f);
    u += 0x7FFFu + ((u >> 16) & 1u);
    return (unsigned short)(u >> 16);
}
__device__ __forceinline__ float bf16_lo(unsigned int u) {
    return __uint_as_float(u << 16);
}
__device__ __forceinline__ float bf16_hi(unsigned int u) {
    return __uint_as_float(u & 0xffff0000u);
}

// ---------- prep: pure streaming (fb/Wt/BN fold) + zero bucketCount ----------
__global__ __launch_bounds__(256) void prep_kernel(
    const float* __restrict__ feats, unsigned short* __restrict__ fb,
    const float* __restrict__ W, unsigned short* __restrict__ Wt,
    const float* __restrict__ gamma, const float* __restrict__ beta,
    const float* __restrict__ rmean, const float* __restrict__ rvar,
    float* __restrict__ bnscale, float* __restrict__ bnshift,
    int* __restrict__ bucketCount)
{
    const int gid = blockIdx.x * 256 + threadIdx.x;
    const int nt = gridDim.x * 256;
    for (int e4i = gid; e4i < (N_VOX * CIN) / 4; e4i += nt) {
        const int e4 = e4i * 4;
        const float4 v = *(const float4*)(feats + e4);
        ushort4 b;
        b.x = f32_to_bf16(v.x);
        b.y = f32_to_bf16(v.y);
        b.z = f32_to_bf16(v.z);
        b.w = f32_to_bf16(v.w);
        *(ushort4*)(fb + e4) = b;
    }
    for (int e = gid; e < K_OFF * CIN * COUT; e += nt) {
        const int k = e / (CIN * COUT);
        const int r = e % (CIN * COUT);
        Wt[k * CIN * COUT + (r % COUT) * CIN + (r / COUT)] = f32_to_bf16(W[e]);
    }
    if (gid < COUT) {
        const float inv = rsqrtf(rvar[gid] + BN_EPS);
        const float sc = inv * gamma[gid];
        bnscale[gid] = sc;
        bnshift[gid] = beta[gid] - rmean[gid] * sc;
    }
    if (gid < NB) bucketCount[gid] = 0;
}

// ---------- phase A: gather-GEMM + embedded bucket-scatter ----------
// Blocks with flat id < PA_GRID first bucket-scatter 4096 pairs (LDS hist +
// ~391 global atomics), then run their conv tiles. The latency/atomic-bound
// sort work hides under the grid's BW-bound GEMM stream. Plain stores keep
// contrib MALL-resident for gather_bn (NT evict-first cost +77MB HBM, r5).
__global__ __launch_bounds__(256) void conv_bucket_kernel(
    const unsigned short* __restrict__ fb, const unsigned short* __restrict__ Wt,
    const int* __restrict__ in_idx, const int* __restrict__ oix,
    unsigned int* __restrict__ recs, int* __restrict__ bucketCount,
    unsigned short* __restrict__ contrib)
{
    __shared__ alignas(16) unsigned short lds[4][16 * 72];
    __shared__ int lhist[NB];
    __shared__ int gbase[NB];
    const int t = threadIdx.x;
    const int k = blockIdx.y;
    const int fid = k * CONV_BLOCKS_X + blockIdx.x;   // 0..2537

    if (fid < PA_GRID) {                              // block-uniform branch
        for (int i = t; i < NB; i += 256) lhist[i] = 0;
        __syncthreads();
        const int base = fid * PA_PAIRS;
        int lp[PPT];
#pragma unroll
        for (int i = 0; i < PPT; ++i) {
            const int e = base + i * 256 + t;
            lp[i] = (e < NPAIR) ? atomicAdd(&lhist[oix[e] >> VB_SHIFT], 1) : 0;
        }
        __syncthreads();
        for (int i = t; i < NB; i += 256) {
            const int c = lhist[i];
            gbase[i] = c ? atomicAdd(&bucketCount[i], c) : 0;
        }
        __syncthreads();
#pragma unroll
        for (int i = 0; i < PPT; ++i) {
            const int e = base + i * 256 + t;
            if (e < NPAIR) {
                const int v = oix[e];
                const int b = v >> VB_SHIFT;
                const int idx = gbase[b] + lp[i];
                if (idx < BCAP)
                    recs[(size_t)b * BCAP + idx] =
                        ((unsigned int)e << VB_SHIFT) | (unsigned int)(v & (VB - 1));
            }
        }
    }

    // ---- conv part (per-wave, no barriers) ----
    const int lane = threadIdx.x & 63;
    const int wid = threadIdx.x >> 6;
    const int w = blockIdx.x * 4 + wid;
    if (w >= WAVES_PER_K) return;
    const int col = lane & 15;
    const int quad = lane >> 4;
    unsigned short* L = lds[wid];

    bf16x8 Bf[4][2];
    const short* Wk = (const short*)(Wt + k * CIN * COUT);
#pragma unroll
    for (int tt = 0; tt < 4; ++tt) {
        const short* p = Wk + (tt * 16 + col) * CIN + quad * 8;
        Bf[tt][0] = *(const bf16x8*)(p);
        Bf[tt][1] = *(const bf16x8*)(p + 32);
    }

    int m0 = k * M_PAIR + (w * TILES_PER_WAVE) * 16;
    {
        const int rin = in_idx[m0 + col];
        const short* fp = (const short*)fb + (size_t)rin * CIN + quad * 8;
        bf16x8 A0 = *(const bf16x8*)(fp);
        bf16x8 A1 = *(const bf16x8*)(fp + 32);

        for (int it = 0; it < TILES_PER_WAVE; ++it) {
            bf16x8 nA0 = A0, nA1 = A1;
            if (it + 1 < TILES_PER_WAVE) {
                const int rn = in_idx[m0 + 16 + col];
                const short* fn = (const short*)fb + (size_t)rn * CIN + quad * 8;
                nA0 = *(const bf16x8*)(fn);
                nA1 = *(const bf16x8*)(fn + 32);
            }

            f32x4 acc[4];
#pragma unroll
            for (int tt = 0; tt < 4; ++tt) {
                f32x4 z = {0.f, 0.f, 0.f, 0.f};
                acc[tt] = __builtin_amdgcn_mfma_f32_16x16x32_bf16(A0, Bf[tt][0], z, 0, 0, 0);
                acc[tt] = __builtin_amdgcn_mfma_f32_16x16x32_bf16(A1, Bf[tt][1], acc[tt], 0, 0, 0);
            }
#pragma unroll
            for (int r = 0; r < 4; ++r) {
                const int row = quad * 4 + r;
#pragma unroll
                for (int tt = 0; tt < 4; ++tt)
                    L[row * 72 + tt * 16 + col] = f32_to_bf16(acc[tt][r]);
            }
#pragma unroll
            for (int itr = 0; itr < 2; ++itr) {
                const int row = itr * 8 + (lane >> 3);
                const int chunk = lane & 7;
                const u16x8 v = *(const u16x8*)(L + row * 72 + chunk * 8);
                *(u16x8*)(contrib + (size_t)(m0 + row) * 64 + chunk * 8) = v;
            }
            A0 = nA0;
            A1 = nA1;
            m0 += 16;
        }
    }
}

// ---------- phase B (fused): quarter-bucket LDS perm + segmented sum + BN/ReLU ----------
// Each block: filter its bucket's recs to 64 voxels -> LDS hist/scan/perm ->
// 4 waves reduce one voxel each (16 rounds). No perm/segcnt in global memory.
__global__ __launch_bounds__(256) void gather_bn_kernel(
    const unsigned int* __restrict__ recs, const int* __restrict__ bucketCount,
    const unsigned short* __restrict__ contrib,
    const float* __restrict__ bnscale, const float* __restrict__ bnshift,
    float* __restrict__ out)
{
    __shared__ int hist[QVOX];
    __shared__ int scan_[QVOX];
    __shared__ int cursor[QVOX];
    __shared__ int lperm[QCAP];
    __shared__ float s_sc[COUT], s_sh[COUT];
    const int blk = blockIdx.x;          // 0 .. NB*QSPLIT-1
    const int b = blk >> 2;
    const int q = blk & 3;
    const int t = threadIdx.x;
    if (t < QVOX) hist[t] = 0;
    if (t < COUT) { s_sc[t] = bnscale[t]; s_sh[t] = bnshift[t]; }
    __syncthreads();
    int bc = bucketCount[b];
    if (bc > BCAP) bc = BCAP;
    const unsigned int* r = recs + (size_t)b * BCAP;
    // pass 1: filtered histogram
    for (int i = t; i < bc; i += 256) {
        const int vl = r[i] & (VB - 1);
        if ((vl >> 6) == q) atomicAdd(&hist[vl & (QVOX - 1)], 1);
    }
    __syncthreads();
    int hc = 0;
    if (t < QVOX) { hc = hist[t]; scan_[t] = hc; }
    __syncthreads();
    for (int o = 1; o < QVOX; o <<= 1) {
        int x = (t < QVOX && t >= o) ? scan_[t - o] : 0;
        __syncthreads();
        if (t < QVOX) scan_[t] += x;
        __syncthreads();
    }
    if (t < QVOX) cursor[t] = scan_[t] - hc;
    __syncthreads();
    // pass 2: scatter pids into LDS perm (recs re-read is L2-hot)
    for (int i = t; i < bc; i += 256) {
        const unsigned int rec = r[i];
        const int vl = rec & (VB - 1);
        if ((vl >> 6) == q) {
            const int lp = atomicAdd(&cursor[vl & (QVOX - 1)], 1);
            if (lp < QCAP) lperm[lp] = (int)(rec >> VB_SHIFT);
        }
    }
    __syncthreads();
    // gather: 4 waves, each reduces 16 voxels sequentially
    const int wid = t >> 6;
    const int lane = t & 63;
    const int rg = lane >> 3;          // row group 0..7
    const int cg = lane & 7;           // channel octet 0..7
    for (int vi = wid; vi < QVOX; vi += 4) {
        const int v = b * VB + q * QVOX + vi;
        if (v >= N_VOX) continue;      // wave-uniform
        int n = hist[vi];
        const int s = scan_[vi] - n;
        if (s + n > QCAP) n = (s < QCAP) ? QCAP - s : 0;

        float a0 = 0.f, a1 = 0.f, a2 = 0.f, a3 = 0.f;
        float a4 = 0.f, a5 = 0.f, a6 = 0.f, a7 = 0.f;
        float b0 = 0.f, b1 = 0.f, b2 = 0.f, b3 = 0.f;
        float b4 = 0.f, b5 = 0.f, b6 = 0.f, b7 = 0.f;
        int j = rg;
        for (; j + 8 < n; j += 16) {   // 2 independent pid->row chains
            const int p0 = lperm[s + j];
            const int p1 = lperm[s + j + 8];
            const u32x4 u = __builtin_nontemporal_load(
                (const u32x4*)(contrib + (size_t)p0 * 64) + cg);
            const u32x4 w = __builtin_nontemporal_load(
                (const u32x4*)(contrib + (size_t)p1 * 64) + cg);
            a0 += bf16_lo(u.x); a1 += bf16_hi(u.x);
            a2 += bf16_lo(u.y); a3 += bf16_hi(u.y);
            a4 += bf16_lo(u.z); a5 += bf16_hi(u.z);
            a6 += bf16_lo(u.w); a7 += bf16_hi(u.w);
            b0 += bf16_lo(w.x); b1 += bf16_hi(w.x);
            b2 += bf16_lo(w.y); b3 += bf16_hi(w.y);
            b4 += bf16_lo(w.z); b5 += bf16_hi(w.z);
            b6 += bf16_lo(w.w); b7 += bf16_hi(w.w);
        }
        for (; j < n; j += 8) {
            const int p0 = lperm[s + j];
            const u32x4 u = __builtin_nontemporal_load(
                (const u32x4*)(contrib + (size_t)p0 * 64) + cg);
            a0 += bf16_lo(u.x); a1 += bf16_hi(u.x);
            a2 += bf16_lo(u.y); a3 += bf16_hi(u.y);
            a4 += bf16_lo(u.z); a5 += bf16_hi(u.z);
            a6 += bf16_lo(u.w); a7 += bf16_hi(u.w);
        }
        a0 += b0; a1 += b1; a2 += b2; a3 += b3;
        a4 += b4; a5 += b5; a6 += b6; a7 += b7;
        a0 += __shfl_xor(a0, 8, 64); a0 += __shfl_xor(a0, 16, 64); a0 += __shfl_xor(a0, 32, 64);
        a1 += __shfl_xor(a1, 8, 64); a1 += __shfl_xor(a1, 16, 64); a1 += __shfl_xor(a1, 32, 64);
        a2 += __shfl_xor(a2, 8, 64); a2 += __shfl_xor(a2, 16, 64); a2 += __shfl_xor(a2, 32, 64);
        a3 += __shfl_xor(a3, 8, 64); a3 += __shfl_xor(a3, 16, 64); a3 += __shfl_xor(a3, 32, 64);
        a4 += __shfl_xor(a4, 8, 64); a4 += __shfl_xor(a4, 16, 64); a4 += __shfl_xor(a4, 32, 64);
        a5 += __shfl_xor(a5, 8, 64); a5 += __shfl_xor(a5, 16, 64); a5 += __shfl_xor(a5, 32, 64);
        a6 += __shfl_xor(a6, 8, 64); a6 += __shfl_xor(a6, 16, 64); a6 += __shfl_xor(a6, 32, 64);
        a7 += __shfl_xor(a7, 8, 64); a7 += __shfl_xor(a7, 16, 64); a7 += __shfl_xor(a7, 32, 64);
        if (rg == 0) {
            const int ch = cg * 8;
            float4 r0, r1;
            r0.x = fmaxf(fmaf(a0, s_sc[ch + 0], s_sh[ch + 0]), 0.f);
            r0.y = fmaxf(fmaf(a1, s_sc[ch + 1], s_sh[ch + 1]), 0.f);
            r0.z = fmaxf(fmaf(a2, s_sc[ch + 2], s_sh[ch + 2]), 0.f);
            r0.w = fmaxf(fmaf(a3, s_sc[ch + 3], s_sh[ch + 3]), 0.f);
            r1.x = fmaxf(fmaf(a4, s_sc[ch + 4], s_sh[ch + 4]), 0.f);
            r1.y = fmaxf(fmaf(a5, s_sc[ch + 5], s_sh[ch + 5]), 0.f);
            r1.z = fmaxf(fmaf(a6, s_sc[ch + 6], s_sh[ch + 6]), 0.f);
            r1.w = fmaxf(fmaf(a7, s_sc[ch + 7], s_sh[ch + 7]), 0.f);
            *(float4*)(out + (size_t)v * 64 + ch) = r0;
            *(float4*)(out + (size_t)v * 64 + ch + 4) = r1;
        }
    }
}

// ---------- fallback (atomic path, used if ws too small) ----------
__global__ __launch_bounds__(256) void prep_small_kernel(
    const float* __restrict__ feats, unsigned short* __restrict__ fb,
    float* __restrict__ out, const float* __restrict__ W,
    unsigned short* __restrict__ Wt)
{
    const int e = blockIdx.x * blockDim.x + threadIdx.x;
    if (e < (N_VOX * CIN) / 4) {
        const int e4 = e * 4;
        const float4 v = *(const float4*)(feats + e4);
        ushort4 b;
        b.x = f32_to_bf16(v.x);
        b.y = f32_to_bf16(v.y);
        b.z = f32_to_bf16(v.z);
        b.w = f32_to_bf16(v.w);
        *(ushort4*)(fb + e4) = b;
        *(float4*)(out + e4) = make_float4(0.f, 0.f, 0.f, 0.f);
    }
    if (e < K_OFF * CIN * COUT) {
        const int k = e / (CIN * COUT);
        const int r = e % (CIN * COUT);
        Wt[k * CIN * COUT + (r % COUT) * CIN + (r / COUT)] = f32_to_bf16(W[e]);
    }
}

__global__ __launch_bounds__(256) void conv_atomic_kernel(
    const unsigned short* __restrict__ fb, const unsigned short* __restrict__ Wt,
    const int* __restrict__ in_idx, const int* __restrict__ out_idx,
    float* __restrict__ out)
{
    const int k = blockIdx.y;
    const int lane = threadIdx.x & 63;
    const int wave = blockIdx.x * 4 + (threadIdx.x >> 6);
    const int col = lane & 15;
    const int quad = lane >> 4;
    bf16x8 Bf[4][2];
    const short* Wk = (const short*)(Wt + k * CIN * COUT);
#pragma unroll
    for (int t = 0; t < 4; ++t) {
        const short* p = Wk + (t * 16 + col) * CIN + quad * 8;
        Bf[t][0] = *(const bf16x8*)(p);
        Bf[t][1] = *(const bf16x8*)(p + 32);
    }
    const int base = k * M_PAIR;
    for (int tile = wave; tile < M_PAIR / 16; tile += 128) {
        const int m0 = base + tile * 16;
        const int rin = in_idx[m0 + col];
        const short* fp = (const short*)fb + (size_t)rin * CIN + quad * 8;
        const bf16x8 A0 = *(const bf16x8*)(fp);
        const bf16x8 A1 = *(const bf16x8*)(fp + 32);
        f32x4 acc[4];
#pragma unroll
        for (int t = 0; t < 4; ++t) {
            f32x4 z = {0.f, 0.f, 0.f, 0.f};
            acc[t] = __builtin_amdgcn_mfma_f32_16x16x32_bf16(A0, Bf[t][0], z, 0, 0, 0);
            acc[t] = __builtin_amdgcn_mfma_f32_16x16x32_bf16(A1, Bf[t][1], acc[t], 0, 0, 0);
        }
        int vo[4];
#pragma unroll
        for (int r = 0; r < 4; ++r) vo[r] = out_idx[m0 + quad * 4 + r];
#pragma unroll
        for (int r = 0; r < 4; ++r) {
            float* op = out + (size_t)vo[r] * COUT + col;
#pragma unroll
            for (int t = 0; t < 4; ++t) atomicAdd(op + t * 16, acc[t][r]);
        }
    }
}

__global__ __launch_bounds__(256) void bn_relu_kernel(
    float* __restrict__ out,
    const float* __restrict__ gamma, const float* __restrict__ beta,
    const float* __restrict__ mean, const float* __restrict__ var)
{
    const int e = blockIdx.x * blockDim.x + threadIdx.x;
    if (e >= N_VOX * COUT) return;
    const int c = e & (COUT - 1);
    const float inv = rsqrtf(var[c] + BN_EPS);
    const float y = (out[e] - mean[c]) * (inv * gamma[c]) + beta[c];
    out[e] = fmaxf(y, 0.f);
}

// ---------- host ----------
extern "C" void kernel_launch(void* const* d_in, const int* in_sizes, int n_in,
                              void* d_out, int out_size, void* d_ws, size_t ws_size,
                              hipStream_t stream) {
    const float* feats = (const float*)d_in[0];
    const float* W     = (const float*)d_in[1];
    const float* gamma = (const float*)d_in[2];
    const float* beta  = (const float*)d_in[3];
    const float* rmean = (const float*)d_in[4];
    const float* rvar  = (const float*)d_in[5];
    const int* in_idx  = (const int*)d_in[6];
    const int* out_idx = (const int*)d_in[7];
    float* out = (float*)d_out;

    char* ws = (char*)d_ws;
    size_t off = 0;
    auto alloc = [&](size_t bytes) {
        size_t p = off;
        off = (off + bytes + 255) & ~(size_t)255;
        return p;
    };
    const size_t o_fb   = alloc((size_t)N_VOX * CIN * 2);
    const size_t o_wt   = alloc((size_t)K_OFF * CIN * COUT * 2);
    const size_t o_bc   = alloc((size_t)NB * 4);              // bucketCount
    const size_t o_recs = alloc((size_t)NB * BCAP * 4);
    const size_t o_bn   = alloc((size_t)2 * COUT * 4);
    const size_t o_ctr  = alloc((size_t)NPAIR * COUT * 2);
    const bool big = (ws_size >= off);       // constant across calls -> graph-safe

    unsigned short* fb  = (unsigned short*)(ws + o_fb);
    unsigned short* Wt  = (unsigned short*)(ws + o_wt);
    int* bucketCount    = (int*)(ws + o_bc);
    unsigned int* recs  = (unsigned int*)(ws + o_recs);
    float* bnscale      = (float*)(ws + o_bn);
    float* bnshift      = bnscale + COUT;
    unsigned short* ctr = (unsigned short*)(ws + o_ctr);

    if (big) {
        prep_kernel<<<2048, 256, 0, stream>>>(
            feats, fb, W, Wt, gamma, beta, rmean, rvar,
            bnscale, bnshift, bucketCount);
        conv_bucket_kernel<<<dim3(CONV_BLOCKS_X, K_OFF), 256, 0, stream>>>(
            fb, Wt, in_idx, out_idx, recs, bucketCount, ctr);
        gather_bn_kernel<<<NB * QSPLIT, 256, 0, stream>>>(
            recs, bucketCount, ctr, bnscale, bnshift, out);
    } else {
        const int ptot = (N_VOX * CIN) / 4;
        prep_small_kernel<<<(ptot + 255) / 256, 256, 0, stream>>>(feats, fb, out, W, Wt);
        conv_atomic_kernel<<<dim3(32, K_OFF), 256, 0, stream>>>(fb, Wt, in_idx, out_idx, out);
        const int total_e = N_VOX * COUT;
        bn_relu_kernel<<<(total_e + 255) / 256, 256, 0, stream>>>(out, gamma, beta, rmean, rvar);
    }
}